// Round 3
// baseline (802.494 us; speedup 1.0000x reference)
//
#include <hip/hip_runtime.h>
#include <stdint.h>

#define NB   4096   // batch rows
#define LDIM 4096   // latent dim
#define KK   10     // k
#define TPB  256

// ws layout:
//   int   meta[NB][32]   : [0..9]=pos, [10..19]=sign, [20..29]=bestm   (512 KB)
//   float ent_rows[NB]   : per-row entropy contribution                 (16 KB)
#define META_STRIDE 32
#define ENT_OFF     (NB * META_STRIDE)   // in 32-bit words

// ---------------- kernel A: selection / sparsemax / meta ----------------
__global__ __launch_bounds__(TPB) void select_sparsemax(
    const float* __restrict__ logits,
    int*   __restrict__ meta,       // [NB,32]
    float* __restrict__ ent_rows,   // [NB]
    float* __restrict__ distr)      // [NB,KK]
{
    __shared__ unsigned long long s_cand[4 * KK];
    __shared__ float s_wsum[4];

    const int b    = blockIdx.x;
    const int t    = threadIdx.x;
    const int lane = t & 63;
    const int wv   = t >> 6;
    const float* __restrict__ row = logits + (size_t)b * LDIM;

    // load 16 logits/thread, coalesced: element idx = (q<<10) + (t<<2) + j
    float vals[16];
#pragma unroll
    for (int q = 0; q < 4; q++) {
        const float4 f = *(const float4*)(row + (q << 10) + (t << 2));
        vals[q*4+0] = f.x; vals[q*4+1] = f.y; vals[q*4+2] = f.z; vals[q*4+3] = f.w;
    }

    // S0 = sum of positive logits (wave reduce -> LDS)
    float s0 = 0.f;
#pragma unroll
    for (int i = 0; i < 16; i++) s0 += vals[i] > 0.f ? vals[i] : 0.f;
#pragma unroll
    for (int off = 1; off < 64; off <<= 1) s0 += __shfl_xor(s0, off, 64);
    if (lane == 0) s_wsum[wv] = s0;

    // stage 1 (wave-local): each wave's 10 smallest |logit|
    // packed u64 = (cost_bits<<32) | (idx<<1) | sign ; u64-min == stable top_k order
    unsigned int taken = 0u;
    for (int c = 0; c < KK; c++) {
        unsigned long long best = ~0ull;
#pragma unroll
        for (int i = 0; i < 16; i++) {
            if (!(taken & (1u << i))) {
                const float val  = vals[i];
                const float cost = fabsf(val);
                const int   idx  = ((i >> 2) << 10) + (t << 2) + (i & 3);
                const unsigned long long pk =
                    ((unsigned long long)__float_as_uint(cost) << 32)
                    | (unsigned)((idx << 1) | (val > 0.f ? 1 : 0));
                if (pk < best) best = pk;
            }
        }
#pragma unroll
        for (int off = 1; off < 64; off <<= 1) {
            const unsigned long long o = __shfl_xor(best, off, 64);
            if (o < best) best = o;
        }
        if (lane == 0) s_cand[wv * KK + c] = best;
        const unsigned lo = (unsigned)best;
        const int idx = (int)(lo >> 1);
        const int rem = idx & 1023;
        if ((rem >> 2) == t) taken |= 1u << (((idx >> 10) << 2) | (rem & 3));
    }
    __syncthreads();

    // wave 0: merge 40 candidates -> global top-10, subset stage, sparsemax
    if (wv == 0) {
        unsigned long long cand = (lane < 4 * KK) ? s_cand[lane] : ~0ull;
        float csm[KK]; int pos[KK]; int sgn[KK];
#pragma unroll
        for (int c = 0; c < KK; c++) {
            unsigned long long w = cand;
#pragma unroll
            for (int off = 1; off < 64; off <<= 1) {
                const unsigned long long o = __shfl_xor(w, off, 64);
                if (o < w) w = o;
            }
            if (cand == w) cand = ~0ull;  // retire winner (packed values distinct)
            const unsigned lo = (unsigned)w;
            pos[c] = (int)(lo >> 1);
            sgn[c] = (int)(lo & 1u);
            csm[c] = __uint_as_float((unsigned)(w >> 32));
        }

        // 1024 subset sums, 16/lane; ascending-bit accumulation == einsum rounding
        float sums[16];
#pragma unroll
        for (int i = 0; i < 16; i++) {
            const int m = (lane << 4) | i;
            float acc = 0.f;
#pragma unroll
            for (int j = 0; j < KK; j++) acc += (m & (1 << j)) ? csm[j] : 0.f;
            sums[i] = acc;
        }
        unsigned int taken2 = 0u;
        int bm[KK]; float cst[KK];
        for (int c = 0; c < KK; c++) {
            unsigned long long best = ~0ull;
#pragma unroll
            for (int i = 0; i < 16; i++) {
                if (!(taken2 & (1u << i))) {
                    const unsigned long long pk =
                        ((unsigned long long)__float_as_uint(sums[i]) << 32)
                        | (unsigned)((lane << 4) | i);
                    if (pk < best) best = pk;
                }
            }
#pragma unroll
            for (int off = 1; off < 64; off <<= 1) {
                const unsigned long long o = __shfl_xor(best, off, 64);
                if (o < best) best = o;
            }
            const int m = (int)(unsigned)best;
            if ((m >> 4) == lane) taken2 |= 1u << (m & 15);
            bm[c]  = m;
            cst[c] = __uint_as_float((unsigned)(best >> 32));
        }

        if (lane == 0) {
            int* mrow = meta + b * META_STRIDE;
#pragma unroll
            for (int c = 0; c < KK; c++) {
                mrow[c]           = pos[c];
                mrow[KK + c]      = sgn[c];
                mrow[2 * KK + c]  = bm[c];
            }
            const float S0 = (s_wsum[0] + s_wsum[1]) + (s_wsum[2] + s_wsum[3]);
            float z[KK];
#pragma unroll
            for (int c = 0; c < KK; c++) z[c] = S0 - cst[c];
            float acc = 0.f; int ks = 0;
#pragma unroll
            for (int r = 1; r <= KK; r++) {
                acc += z[r-1];
                if (1.f + (float)r * z[r-1] > acc) ks++;
            }
            float acc2 = 0.f;
#pragma unroll
            for (int r = 0; r < KK; r++) if (r < ks) acc2 += z[r];
            const float tau = (acc2 - 1.f) / (float)ks;
            float entl = 0.f;
            float* drow = distr + b * KK;
#pragma unroll
            for (int c = 0; c < KK; c++) {
                float p = z[c] - tau;
                p = p > 0.f ? p : 0.f;
                drow[c] = p;
                if (p > 0.f) entl -= p * logf(p);
            }
            ent_rows[b] = entl;
        }
    }
}

// ---------------- kernel B: pure streaming bv writer ----------------
__global__ __launch_bounds__(TPB) void bv_write(
    const float* __restrict__ logits,
    const int*   __restrict__ meta,
    float*       __restrict__ bv)
{
    const int c   = blockIdx.x;   // 0..KK-1
    const int row = blockIdx.y;   // 0..NB-1
    const int t   = threadIdx.x;
    const float* __restrict__ lrow = logits + (size_t)row * LDIM;
    float* __restrict__ orow = bv + ((size_t)row * KK + c) * LDIM;

#pragma unroll
    for (int q = 0; q < 4; q++) {
        const float4 f = *(const float4*)(lrow + (q << 10) + (t << 2));
        float4 o;
        o.x = f.x > 0.f ? 1.f : 0.f;
        o.y = f.y > 0.f ? 1.f : 0.f;
        o.z = f.z > 0.f ? 1.f : 0.f;
        o.w = f.w > 0.f ? 1.f : 0.f;
        *(float4*)(orow + (q << 10) + (t << 2)) = o;
    }

    __syncthreads();  // drain bulk stores before scattered overwrite
    if (t < KK) {
        const int* mrow = meta + row * META_STRIDE;
        const int bm = mrow[2 * KK + c];
        if ((bm >> t) & 1) {
            const int pos = mrow[t];
            const int sgn = mrow[KK + t];
            orow[pos] = sgn ? 0.f : 1.f;
        }
    }
}

// ---------------- kernel D: entropy reduction ----------------
__global__ __launch_bounds__(TPB) void ent_reduce(
    const float* __restrict__ ent_rows,
    float* __restrict__ ent)
{
    __shared__ float s_w[4];
    const int t = threadIdx.x, lane = t & 63, wv = t >> 6;
    float s = 0.f;
#pragma unroll
    for (int i = 0; i < NB / TPB; i++) s += ent_rows[i * TPB + t];
#pragma unroll
    for (int off = 1; off < 64; off <<= 1) s += __shfl_xor(s, off, 64);
    if (lane == 0) s_w[wv] = s;
    __syncthreads();
    if (t == 0)
        ent[0] = ((s_w[0] + s_w[1]) + (s_w[2] + s_w[3])) * (1.0f / (float)NB);
}

extern "C" void kernel_launch(void* const* d_in, const int* in_sizes, int n_in,
                              void* d_out, int out_size, void* d_ws, size_t ws_size,
                              hipStream_t stream)
{
    const float* logits = (const float*)d_in[0];
    float* out   = (float*)d_out;
    float* bv    = out;
    float* distr = out + (size_t)NB * KK * LDIM;
    float* ent   = distr + (size_t)NB * KK;
    int*   meta     = (int*)d_ws;
    float* ent_rows = (float*)d_ws + ENT_OFF;

    select_sparsemax<<<dim3(NB), dim3(TPB), 0, stream>>>(logits, meta, ent_rows, distr);
    bv_write<<<dim3(KK, NB), dim3(TPB), 0, stream>>>(logits, meta, bv);
    ent_reduce<<<dim3(1), dim3(TPB), 0, stream>>>(ent_rows, ent);
}

// Round 5
// 732.330 us; speedup vs baseline: 1.0958x; 1.0958x over previous
//
#include <hip/hip_runtime.h>
#include <stdint.h>

#define NB   4096   // batch rows
#define LDIM 4096   // latent dim
#define KK   10     // k
#define TPB  256

// raw vector type: __builtin_nontemporal_* requires a real vector, not HIP_vector_type
typedef float vf4 __attribute__((ext_vector_type(4)));

// ws layout: float ent_rows[NB]  (16 KB)

__global__ __launch_bounds__(TPB) void topk_sparsemax(
    const float* __restrict__ logits,
    float* __restrict__ bv,        // [NB, KK, LDIM]
    float* __restrict__ distr,     // [NB, KK]
    float* __restrict__ ent_rows)  // [NB]
{
    __shared__ unsigned long long s_cand[4 * KK];
    __shared__ float s_wsum[4];
    __shared__ int   s_pos[KK];
    __shared__ int   s_sign[KK];
    __shared__ int   s_bestm[KK];

    const int b    = blockIdx.x;
    const int t    = threadIdx.x;
    const int lane = t & 63;
    const int wv   = t >> 6;
    const float* __restrict__ row = logits + (size_t)b * LDIM;

    // ---- load 16 logits/thread, coalesced, nontemporal (read-once stream)
    float vals[16];
#pragma unroll
    for (int q = 0; q < 4; q++) {
        const vf4 f = __builtin_nontemporal_load((const vf4*)(row + (q << 10) + (t << 2)));
        vals[q*4+0] = f.x; vals[q*4+1] = f.y; vals[q*4+2] = f.z; vals[q*4+3] = f.w;
    }

    // ---- bulk bv base write FIRST (streams on vmem pipe during selection),
    //      nontemporal: 671 MB written once, never re-read by us
    vf4 base4[4];
#pragma unroll
    for (int q = 0; q < 4; q++) {
        base4[q].x = vals[q*4+0] > 0.f ? 1.f : 0.f;
        base4[q].y = vals[q*4+1] > 0.f ? 1.f : 0.f;
        base4[q].z = vals[q*4+2] > 0.f ? 1.f : 0.f;
        base4[q].w = vals[q*4+3] > 0.f ? 1.f : 0.f;
    }
    float* out0 = bv + (size_t)b * (KK * LDIM);
#pragma unroll
    for (int c = 0; c < KK; c++) {
        float* orow = out0 + c * LDIM + (t << 2);
#pragma unroll
        for (int q = 0; q < 4; q++)
            __builtin_nontemporal_store(base4[q], (vf4*)(orow + (q << 10)));
    }

    // ---- S0 = sum of positive logits (wave reduce -> LDS; combined later)
    float s0 = 0.f;
#pragma unroll
    for (int i = 0; i < 16; i++) s0 += vals[i] > 0.f ? vals[i] : 0.f;
#pragma unroll
    for (int off = 1; off < 64; off <<= 1) s0 += __shfl_xor(s0, off, 64);
    if (lane == 0) s_wsum[wv] = s0;

    // ---- stage 1 (wave-local, zero barriers): each wave's 10 smallest |logit|
    // packed u64 = (cost_bits<<32) | (idx<<1) | sign ; u64-min == stable top_k order
    unsigned int taken = 0u;
    for (int c = 0; c < KK; c++) {
        unsigned long long best = ~0ull;
#pragma unroll
        for (int i = 0; i < 16; i++) {
            if (!(taken & (1u << i))) {
                const float val  = vals[i];
                const float cost = fabsf(val);
                const int   idx  = ((i >> 2) << 10) + (t << 2) + (i & 3);
                const unsigned long long pk =
                    ((unsigned long long)__float_as_uint(cost) << 32)
                    | (unsigned)((idx << 1) | (val > 0.f ? 1 : 0));
                if (pk < best) best = pk;
            }
        }
#pragma unroll
        for (int off = 1; off < 64; off <<= 1) {
            const unsigned long long o = __shfl_xor(best, off, 64);
            if (o < best) best = o;
        }
        if (lane == 0) s_cand[wv * KK + c] = best;
        const unsigned lo = (unsigned)best;
        const int idx = (int)(lo >> 1);
        const int rem = idx & 1023;
        if ((rem >> 2) == t) taken |= 1u << (((idx >> 10) << 2) | (rem & 3));
    }
    __syncthreads();  // publishes candidates; also drains bulk stores

    // ---- wave 0: merge 40 candidates -> global top-10, subset stage, sparsemax
    if (wv == 0) {
        unsigned long long cand = (lane < 4 * KK) ? s_cand[lane] : ~0ull;
        float csm[KK]; int pos[KK]; int sgn[KK];
#pragma unroll
        for (int c = 0; c < KK; c++) {
            unsigned long long w = cand;
#pragma unroll
            for (int off = 1; off < 64; off <<= 1) {
                const unsigned long long o = __shfl_xor(w, off, 64);
                if (o < w) w = o;
            }
            if (cand == w) cand = ~0ull;  // retire winner (packed values distinct)
            const unsigned lo = (unsigned)w;
            pos[c] = (int)(lo >> 1);
            sgn[c] = (int)(lo & 1u);
            csm[c] = __uint_as_float((unsigned)(w >> 32));
        }

        // 1024 subset sums, 16/lane; ascending-bit accumulation == einsum rounding
        float sums[16];
#pragma unroll
        for (int i = 0; i < 16; i++) {
            const int m = (lane << 4) | i;
            float acc = 0.f;
#pragma unroll
            for (int j = 0; j < KK; j++) acc += (m & (1 << j)) ? csm[j] : 0.f;
            sums[i] = acc;
        }
        unsigned int taken2 = 0u;
        int bm[KK]; float cst[KK];
        for (int c = 0; c < KK; c++) {
            unsigned long long best = ~0ull;
#pragma unroll
            for (int i = 0; i < 16; i++) {
                if (!(taken2 & (1u << i))) {
                    const unsigned long long pk =
                        ((unsigned long long)__float_as_uint(sums[i]) << 32)
                        | (unsigned)((lane << 4) | i);
                    if (pk < best) best = pk;
                }
            }
#pragma unroll
            for (int off = 1; off < 64; off <<= 1) {
                const unsigned long long o = __shfl_xor(best, off, 64);
                if (o < best) best = o;
            }
            const int m = (int)(unsigned)best;
            if ((m >> 4) == lane) taken2 |= 1u << (m & 15);
            bm[c]  = m;
            cst[c] = __uint_as_float((unsigned)(best >> 32));
        }

        if (lane == 0) {
#pragma unroll
            for (int c = 0; c < KK; c++) {
                s_pos[c] = pos[c]; s_sign[c] = sgn[c]; s_bestm[c] = bm[c];
            }
            const float S0 = (s_wsum[0] + s_wsum[1]) + (s_wsum[2] + s_wsum[3]);
            float z[KK];
#pragma unroll
            for (int c = 0; c < KK; c++) z[c] = S0 - cst[c];
            float acc = 0.f; int ks = 0;
#pragma unroll
            for (int r = 1; r <= KK; r++) {
                acc += z[r-1];
                if (1.f + (float)r * z[r-1] > acc) ks++;
            }
            float acc2 = 0.f;
#pragma unroll
            for (int r = 0; r < KK; r++) if (r < ks) acc2 += z[r];
            const float tau = (acc2 - 1.f) / (float)ks;
            float entl = 0.f;
            float* drow = distr + b * KK;
#pragma unroll
            for (int c = 0; c < KK; c++) {
                float p = z[c] - tau;
                p = p > 0.f ? p : 0.f;
                drow[c] = p;
                if (p > 0.f) entl -= p * logf(p);
            }
            ent_rows[b] = entl;
        }
    }
    __syncthreads();

    // ---- flip fixup: bulk stores drained at barrier 1, so these overwrite safely
    if (t < KK * KK) {
        const int c = t / KK, j = t % KK;
        if ((s_bestm[c] >> j) & 1)
            out0[c * LDIM + s_pos[j]] = s_sign[j] ? 0.f : 1.f;
    }
}

__global__ __launch_bounds__(TPB) void ent_reduce(
    const float* __restrict__ ent_rows,
    float* __restrict__ ent)
{
    __shared__ float s_w[4];
    const int t = threadIdx.x, lane = t & 63, wv = t >> 6;
    float s = 0.f;
#pragma unroll
    for (int i = 0; i < NB / TPB; i++) s += ent_rows[i * TPB + t];
#pragma unroll
    for (int off = 1; off < 64; off <<= 1) s += __shfl_xor(s, off, 64);
    if (lane == 0) s_w[wv] = s;
    __syncthreads();
    if (t == 0)
        ent[0] = ((s_w[0] + s_w[1]) + (s_w[2] + s_w[3])) * (1.0f / (float)NB);
}

extern "C" void kernel_launch(void* const* d_in, const int* in_sizes, int n_in,
                              void* d_out, int out_size, void* d_ws, size_t ws_size,
                              hipStream_t stream)
{
    const float* logits = (const float*)d_in[0];
    float* out   = (float*)d_out;
    float* bv    = out;
    float* distr = out + (size_t)NB * KK * LDIM;
    float* ent   = distr + (size_t)NB * KK;
    float* ent_rows = (float*)d_ws;

    topk_sparsemax<<<dim3(NB), dim3(TPB), 0, stream>>>(logits, bv, distr, ent_rows);
    ent_reduce<<<dim3(1), dim3(TPB), 0, stream>>>(ent_rows, ent);
}